// Round 4
// baseline (97.504 us; speedup 1.0000x reference)
//
#include <hip/hip_runtime.h>

#define K      32
#define TPB    256
#define NB     2048                 // NB*TPB float4-slots * 4 = NTOT
#define NTOT   (32 * 64 * 1024)     // 2,097,152
#define CL2    14.4269504088896341f // c*log2(e), c = -ALPHA = 10
#define TFLOATS 232                 // 7 rows * 33 + epsb

__device__ __forceinline__ float wave_reduce_sum(float v) {
#pragma unroll
  for (int m = 1; m < 64; m <<= 1) v += __shfl_xor(v, m, 64);
  return v;
}

// Round-4 theory: three structural rewrites of ssq_main moved total by ~0.
// Either (H0) two serial 41us poison fills own the budget, or (H1) main is
// pinned at ~38us by the one invariant: ~8 ops x 67M (elem,bin) pairs.
// This round makes per-element cost K-INDEPENDENT via sorted-bin
// factorization: t_k = e^{-cx}*e^{c sb_k} (k<idx) / e^{cx}*e^{-c sb_k}
// (k>=idx), so s, bit_code numerator, and sum-sqrt collapse to
// e^{+-cx} * prefix/suffix tables[idx]; per-bin entropy sums become two
// bucket accumulations u=e^{-cx}/s, v=e^{cx}/s unfolded in the tail:
// P_k = e^{c sb_k}*U_k + e^{-c sb_k}*V_k, U_k = sum_{i>k} bU[i],
// V_k = sum_{i<=k} bV[i]. Dead buckets bU[0]/bV[32] absorb the huge
// tail-element u/v values and are never read; all consumed magnitudes
// bounded ~e^{33}. H1 -> ~52-58us; H0 -> unchanged -> roofline.

// prep: 1 wave. Sort bins (rank via shfl), build 33-entry tables in ws.
__global__ void ssq_prep(const float* __restrict__ bins, float* __restrict__ tg) {
  const int lane = threadIdx.x;              // 64 threads = 1 wave
  float bv = (lane < K) ? bins[lane] : 0.f;
  int rank = 0;
#pragma unroll
  for (int j = 0; j < K; ++j) {
    float bj = __shfl(bv, j, 64);
    rank += (bj < bv) || (bj == bv && j < lane);
  }
  __shared__ float sb[K];
  if (lane < K) sb[rank] = bv;
  __syncthreads();
  if (lane <= K) {                           // 33 lanes build prefix/suffix
    float A = 0.f, B = 0.f, Ab = 0.f, Bb = 0.f, Ah = 0.f, Bh = 0.f;
    for (int k = 0; k < K; ++k) {
      float s   = sb[k];
      float e   = __builtin_amdgcn_exp2f( CL2 * s);          // e^{c sb}
      float em  = __builtin_amdgcn_exp2f(-CL2 * s);          // e^{-c sb}
      float eh  = __builtin_amdgcn_exp2f( 0.5f * CL2 * s);   // e^{c sb/2}
      float ehm = __builtin_amdgcn_exp2f(-0.5f * CL2 * s);   // e^{-c sb/2}
      if (k < lane) { A += e;  Ab = fmaf(s, e,  Ab); Ah += eh;  }
      else          { B += em; Bb = fmaf(s, em, Bb); Bh += ehm; }
    }
    tg[ 33 + lane] = A;  tg[ 66 + lane] = B;
    tg[ 99 + lane] = Ab; tg[132 + lane] = Bb;
    tg[165 + lane] = Ah; tg[198 + lane] = Bh;
  }
  if (lane < K) tg[lane] = sb[lane];
  if (lane == 0) {
    tg[K] = 0.f;                             // row-0 pad slot (never probed)
    float bs = 0.f;
    for (int k = 0; k < K; ++k) bs += sb[k];
    tg[231] = 1e-10f * bs;                   // eps * sum(bins)
  }
}

__device__ __forceinline__ void ssq_elem(float xv, const float* __restrict__ Tf,
                                         float* __restrict__ bU,
                                         float* __restrict__ bV,
                                         float epsb, float& q, float& bit) {
  // branchless upper_bound: idx = #{k: sb[k] <= x} in [0,32], 6 LDS probes
  const float* sb = Tf;
  int b_ = 0;
  b_ += (sb[b_ + 15] <= xv) ? 16 : 0;
  b_ += (sb[b_ +  7] <= xv) ?  8 : 0;
  b_ += (sb[b_ +  3] <= xv) ?  4 : 0;
  b_ += (sb[b_ +  1] <= xv) ?  2 : 0;
  b_ += (sb[b_]      <= xv) ?  1 : 0;
  b_ += (sb[b_]      <= xv) ?  1 : 0;        // max before this line is 31
  float ex   = __builtin_amdgcn_exp2f(CL2 * xv);  // e^{c x}
  float exm  = __builtin_amdgcn_rcpf(ex);         // e^{-c x}
  float exh  = __builtin_amdgcn_sqrtf(ex);        // e^{c x/2}
  float exhm = __builtin_amdgcn_rsqf(ex);         // e^{-c x/2}
  float A  = Tf[ 33 + b_], B  = Tf[ 66 + b_];
  float Ab = Tf[ 99 + b_], Bb = Tf[132 + b_];
  float Ah = Tf[165 + b_], Bh = Tf[198 + b_];
  float s   = fmaf(exm, A, ex * B);               // softmax denominator
  float inv = __builtin_amdgcn_rcpf(s);
  bit = fmaf(fmaf(exm, Ab, ex * Bb), inv, epsb);  // sum a_k b_k + eps*sum b
  float h = fmaf(exhm, Ah, exh * Bh);             // sum sqrt(t_k)
  q = fmaf(h, __builtin_amdgcn_rsqf(s), q);       // += sum sqrt(a_k)
  atomicAdd(&bU[b_], exm * inv);                  // idx=0 -> dead bucket
  atomicAdd(&bV[b_], ex * inv);                   // idx=32 -> dead bucket
}

__global__ __launch_bounds__(TPB, 8)
void ssq_main(const float4* __restrict__ x4, const float* __restrict__ tg,
              float4* __restrict__ out4, float* __restrict__ partials) {
  const int tid = threadIdx.x;
  __shared__ float Tf[TFLOATS];
  __shared__ float bU[K + 1], bV[K + 1];
  __shared__ float qr[4];
  if (tid < TFLOATS) Tf[tid] = tg[tid];
  if (tid < K + 1) { bU[tid] = 0.f; bV[tid] = 0.f; }
  __syncthreads();
  const float epsb = Tf[231];

  const int gid = blockIdx.x * TPB + tid;    // one float4 = 4 elements/thread
  float4 X = x4[gid];
  float q = 0.f;
  float4 O;
  ssq_elem(X.x, Tf, bU, bV, epsb, q, O.x);
  ssq_elem(X.y, Tf, bU, bV, epsb, q, O.y);
  ssq_elem(X.z, Tf, bU, bV, epsb, q, O.z);
  ssq_elem(X.w, Tf, bU, bV, epsb, q, O.w);
  out4[gid] = O;

  const int lane = tid & 63, wv = tid >> 6;
  float qs = wave_reduce_sum(q);
  if (lane == 0) qr[wv] = qs;
  __syncthreads();
  // rows 0..31: bU[1..32]; rows 32..63: bV[0..31]; row 64: q
  if (tid < K)           partials[tid * NB + blockIdx.x] = bU[tid + 1];
  else if (tid < 2 * K)  partials[tid * NB + blockIdx.x] = bV[tid - K];
  else if (tid == 2 * K) partials[2 * K * NB + blockIdx.x] =
                             qr[0] + qr[1] + qr[2] + qr[3];
}

// ONE block, 1024 threads: sum 65 partial rows, prefix/suffix unfold,
// entropy + quant + tails.
__global__ __launch_bounds__(1024)
void ssq_tail(const float* __restrict__ partials, const float* __restrict__ tg,
              float* __restrict__ out) {
  const int tid = threadIdx.x;
  const int wv = tid >> 6, lane = tid & 63;
  __shared__ float S[2 * K + 1];
  for (int r = wv; r < 2 * K + 1; r += 16) {
    const float4* p = reinterpret_cast<const float4*>(partials + r * NB);
    float s = 0.f;
#pragma unroll
    for (int c = 0; c < NB / 256; ++c) {     // 8 x float4 per lane
      float4 v = p[c * 64 + lane];
      s += (v.x + v.y) + (v.z + v.w);
    }
    s = wave_reduce_sum(s);
    if (lane == 0) S[r] = s;
  }
  __syncthreads();
  if (wv == 0) {
    float e = 0.f;
    if (lane < K) {
      float U = 0.f, V = 0.f;
      for (int r = 0; r < K; ++r) {          // U_k: rows r>=k; V_k: rows r<=k
        U += (r >= lane) ? S[r] : 0.f;
        V += (r <= lane) ? S[K + r] : 0.f;
      }
      float sbk = tg[lane];
      float P = fmaf(__builtin_amdgcn_exp2f(CL2 * sbk), U,
                     __builtin_amdgcn_exp2f(-CL2 * sbk) * V);
      float p = P * (1.0f / (float)NTOT) + 1e-10f;
      e = -p * __logf(p);
    }
    e = wave_reduce_sum(e);
    if (lane == 0) {
      out[NTOT + 0] = e;                              // code entropy
      out[NTOT + 1] = 0.f;                            // TAU
      out[NTOT + 2] = S[2 * K] * (1.0f / (float)NTOT); // quant loss
      out[NTOT + 3] = 0.f;                            // TAU2
    }
  }
}

extern "C" void kernel_launch(void* const* d_in, const int* in_sizes, int n_in,
                              void* d_out, int out_size, void* d_ws, size_t ws_size,
                              hipStream_t stream) {
  const float* x    = (const float*)d_in[0];
  const float* bins = (const float*)d_in[1];
  float* out        = (float*)d_out;
  float* tg         = (float*)d_ws;           // 232 floats (tables, rounded 256)
  float* partials   = tg + 256;               // 65 * NB floats = 532 KB

  ssq_prep<<<1,  64,   0, stream>>>(bins, tg);
  ssq_main<<<NB, TPB,  0, stream>>>((const float4*)x, tg, (float4*)out, partials);
  ssq_tail<<<1,  1024, 0, stream>>>(partials, tg, out);
}

// Round 5
// 97.475 us; speedup vs baseline: 1.0003x; 1.0003x over previous
//
#include <hip/hip_runtime.h>

#define K      32
#define TPB    256
#define NB     2048                 // NB*TPB float4-slots * 4 = NTOT
#define NTOT   (32 * 64 * 1024)     // 2,097,152
#define CL2    14.4269504088896341f // c*log2(e), c = -ALPHA = 10
// tg layout (floats): [0..32] sorted bins (+pad), [36..167] float4 T4 (A,B,Ab,Bb),
// [168..233] float2 T2 (Ah,Bh), [234] epsb
#define TG_T4   36
#define TG_T2   168
#define TG_EPSB 234

__device__ __forceinline__ float wave_reduce_sum(float v) {
#pragma unroll
  for (int m = 1; m < 64; m <<= 1) v += __shfl_xor(v, m, 64);
  return v;
}

// Round-5 theory: R4's +14.5us regression was the LDS PIPE, not the algorithm:
// ~13 scalar ds_read_b32 gathers/element (6 dependent probes + 7 random-index
// table reads, bank-conflicted) = ~594K LDS wave-insts -> ~7-10us/CU of LDS
// serialization. The factorized math itself passed (absmax 0.0078). Fix:
// pack tables into float4(A,B,Ab,Bb) + float2(Ah,Bh) -> per element
// 6 probes + 1 ds_read_b128 + 1 ds_read_b64 (~2.5x less LDS pipe time).
// Atomics kept (minor). launch_bounds relaxed to (TPB,4) so the 4-wide-ILP
// body can't be forced into spills by a <=64-VGPR cap (R4 confound).
// If total returns to ~83 with kernels now ~5us, the plateau is harness
// floor (41.5us ws-poison fill + reset dispatch swarm) -> roofline.

// prep: 1 wave. Sort bins (rank via shfl), build packed tables in ws.
__global__ void ssq_prep(const float* __restrict__ bins, float* __restrict__ tg) {
  const int lane = threadIdx.x;              // 64 threads = 1 wave
  float bv = (lane < K) ? bins[lane] : 0.f;
  int rank = 0;
#pragma unroll
  for (int j = 0; j < K; ++j) {
    float bj = __shfl(bv, j, 64);
    rank += (bj < bv) || (bj == bv && j < lane);
  }
  __shared__ float sb[K];
  if (lane < K) sb[rank] = bv;
  __syncthreads();
  if (lane <= K) {                           // 33 lanes build prefix/suffix
    float A = 0.f, B = 0.f, Ab = 0.f, Bb = 0.f, Ah = 0.f, Bh = 0.f;
    for (int k = 0; k < K; ++k) {
      float s   = sb[k];
      float e   = __builtin_amdgcn_exp2f( CL2 * s);          // e^{c sb}
      float em  = __builtin_amdgcn_exp2f(-CL2 * s);          // e^{-c sb}
      float eh  = __builtin_amdgcn_exp2f( 0.5f * CL2 * s);   // e^{c sb/2}
      float ehm = __builtin_amdgcn_exp2f(-0.5f * CL2 * s);   // e^{-c sb/2}
      if (k < lane) { A += e;  Ab = fmaf(s, e,  Ab); Ah += eh;  }
      else          { B += em; Bb = fmaf(s, em, Bb); Bh += ehm; }
    }
    reinterpret_cast<float4*>(tg + TG_T4)[lane] = make_float4(A, B, Ab, Bb);
    reinterpret_cast<float2*>(tg + TG_T2)[lane] = make_float2(Ah, Bh);
  }
  if (lane < K) tg[lane] = sb[lane];
  if (lane == 0) {
    tg[K] = 0.f;                             // pad (never probed)
    float bs = 0.f;
    for (int k = 0; k < K; ++k) bs += sb[k];
    tg[TG_EPSB] = 1e-10f * bs;               // eps * sum(bins)
  }
}

__device__ __forceinline__ void ssq_elem(float xv, const float* __restrict__ sbt,
                                         const float4* __restrict__ T4s,
                                         const float2* __restrict__ T2s,
                                         float* __restrict__ bU,
                                         float* __restrict__ bV,
                                         float epsb, float& q, float& bit) {
  // branchless upper_bound: idx = #{k: sb[k] <= x} in [0,32], 6 LDS probes
  int b_ = 0;
  b_ += (sbt[15]      <= xv) ? 16 : 0;
  b_ += (sbt[b_ +  7] <= xv) ?  8 : 0;
  b_ += (sbt[b_ +  3] <= xv) ?  4 : 0;
  b_ += (sbt[b_ +  1] <= xv) ?  2 : 0;
  b_ += (sbt[b_]      <= xv) ?  1 : 0;
  b_ += (sbt[b_]      <= xv) ?  1 : 0;       // max index probed is 31
  float ex   = __builtin_amdgcn_exp2f(CL2 * xv);  // e^{c x}
  float exm  = __builtin_amdgcn_rcpf(ex);         // e^{-c x}
  float exh  = __builtin_amdgcn_sqrtf(ex);        // e^{c x/2}
  float exhm = __builtin_amdgcn_rsqf(ex);         // e^{-c x/2}
  float4 t4 = T4s[b_];                            // one ds_read_b128
  float2 t2 = T2s[b_];                            // one ds_read_b64
  float s   = fmaf(exm, t4.x, ex * t4.y);         // softmax denominator
  float inv = __builtin_amdgcn_rcpf(s);
  bit = fmaf(fmaf(exm, t4.z, ex * t4.w), inv, epsb);  // sum a_k b_k + eps*sum b
  float h = fmaf(exhm, t2.x, exh * t2.y);         // sum sqrt(t_k)
  q = fmaf(h, __builtin_amdgcn_rsqf(s), q);       // += sum sqrt(a_k)
  atomicAdd(&bU[b_], exm * inv);                  // idx=0 -> dead bucket
  atomicAdd(&bV[b_], ex * inv);                   // idx=32 -> dead bucket
}

__global__ __launch_bounds__(TPB, 4)
void ssq_main(const float4* __restrict__ x4, const float* __restrict__ tg,
              float4* __restrict__ out4, float* __restrict__ partials) {
  const int tid = threadIdx.x;
  __shared__ float  sbt[36];
  __shared__ float4 T4s[33];
  __shared__ float2 T2s[33];
  __shared__ float  bU[K + 1], bV[K + 1];
  __shared__ float  qr[4];
  if (tid < 33) {
    sbt[tid] = tg[tid];
    T4s[tid] = reinterpret_cast<const float4*>(tg + TG_T4)[tid];
    T2s[tid] = reinterpret_cast<const float2*>(tg + TG_T2)[tid];
  }
  if (tid < K + 1) { bU[tid] = 0.f; bV[tid] = 0.f; }
  const float epsb = tg[TG_EPSB];            // uniform -> scalar load
  __syncthreads();

  const int gid = blockIdx.x * TPB + tid;    // one float4 = 4 elements/thread
  float4 X = x4[gid];
  float q = 0.f;
  float4 O;
  ssq_elem(X.x, sbt, T4s, T2s, bU, bV, epsb, q, O.x);
  ssq_elem(X.y, sbt, T4s, T2s, bU, bV, epsb, q, O.y);
  ssq_elem(X.z, sbt, T4s, T2s, bU, bV, epsb, q, O.z);
  ssq_elem(X.w, sbt, T4s, T2s, bU, bV, epsb, q, O.w);
  out4[gid] = O;

  const int lane = tid & 63, wv = tid >> 6;
  float qs = wave_reduce_sum(q);
  if (lane == 0) qr[wv] = qs;
  __syncthreads();
  // rows 0..31: bU[1..32]; rows 32..63: bV[0..31]; row 64: q
  if (tid < K)           partials[tid * NB + blockIdx.x] = bU[tid + 1];
  else if (tid < 2 * K)  partials[tid * NB + blockIdx.x] = bV[tid - K];
  else if (tid == 2 * K) partials[2 * K * NB + blockIdx.x] =
                             qr[0] + qr[1] + qr[2] + qr[3];
}

// ONE block, 1024 threads: sum 65 partial rows, prefix/suffix unfold,
// entropy + quant + tails.
__global__ __launch_bounds__(1024)
void ssq_tail(const float* __restrict__ partials, const float* __restrict__ tg,
              float* __restrict__ out) {
  const int tid = threadIdx.x;
  const int wv = tid >> 6, lane = tid & 63;
  __shared__ float S[2 * K + 1];
  for (int r = wv; r < 2 * K + 1; r += 16) {
    const float4* p = reinterpret_cast<const float4*>(partials + r * NB);
    float s = 0.f;
#pragma unroll
    for (int c = 0; c < NB / 256; ++c) {     // 8 x float4 per lane
      float4 v = p[c * 64 + lane];
      s += (v.x + v.y) + (v.z + v.w);
    }
    s = wave_reduce_sum(s);
    if (lane == 0) S[r] = s;
  }
  __syncthreads();
  if (wv == 0) {
    float e = 0.f;
    if (lane < K) {
      float U = 0.f, V = 0.f;
      for (int r = 0; r < K; ++r) {          // U_k: rows r>=k; V_k: rows r<=k
        U += (r >= lane) ? S[r] : 0.f;
        V += (r <= lane) ? S[K + r] : 0.f;
      }
      float sbk = tg[lane];
      float P = fmaf(__builtin_amdgcn_exp2f(CL2 * sbk), U,
                     __builtin_amdgcn_exp2f(-CL2 * sbk) * V);
      float p = P * (1.0f / (float)NTOT) + 1e-10f;
      e = -p * __logf(p);
    }
    e = wave_reduce_sum(e);
    if (lane == 0) {
      out[NTOT + 0] = e;                              // code entropy
      out[NTOT + 1] = 0.f;                            // TAU
      out[NTOT + 2] = S[2 * K] * (1.0f / (float)NTOT); // quant loss
      out[NTOT + 3] = 0.f;                            // TAU2
    }
  }
}

extern "C" void kernel_launch(void* const* d_in, const int* in_sizes, int n_in,
                              void* d_out, int out_size, void* d_ws, size_t ws_size,
                              hipStream_t stream) {
  const float* x    = (const float*)d_in[0];
  const float* bins = (const float*)d_in[1];
  float* out        = (float*)d_out;
  float* tg         = (float*)d_ws;           // 256 floats (packed tables)
  float* partials   = tg + 256;               // 65 * NB floats = 532 KB

  ssq_prep<<<1,  64,   0, stream>>>(bins, tg);
  ssq_main<<<NB, TPB,  0, stream>>>((const float4*)x, tg, (float4*)out, partials);
  ssq_tail<<<1,  1024, 0, stream>>>(partials, tg, out);
}

// Round 6
// 82.437 us; speedup vs baseline: 1.1828x; 1.1824x over previous
//
#include <hip/hip_runtime.h>

#define K      32
#define KH     16                   // bins per lane (K split across lane pairs)
#define TPB    256
#define NB     2048                 // blocks: 2048 * 128 pair-slots * 8 = N
#define EPT    8                    // elements per pair-slot
#define NTOT   (32 * 64 * 1024)     // 2,097,152
#define PSTRIDE (NB * (TPB / 2))    // 262144 pair-slots per sweep

__device__ __forceinline__ float wave_reduce_sum(float v) {
#pragma unroll
  for (int m = 1; m < 64; m <<= 1) v += __shfl_xor(v, m, 64);
  return v;
}

// xor-1 neighbor add via DPP quad_perm(1,0,3,2): VALU-only, no LDS pipe.
__device__ __forceinline__ float dpp_xor1_add(float v) {
  int sw = __builtin_amdgcn_update_dpp(0, __builtin_bit_cast(int, v),
                                       0xB1, 0xF, 0xF, true);
  return v + __builtin_bit_cast(float, sw);
}
// xor-2 via quad_perm(2,3,0,1) = 0x4E
__device__ __forceinline__ float dpp_xor2_add(float v) {
  int sw = __builtin_amdgcn_update_dpp(0, __builtin_bit_cast(int, v),
                                       0x4E, 0xF, 0xF, true);
  return v + __builtin_bit_cast(float, sw);
}
// xor-8 via row_ror:8 (rotation by 8 within a 16-lane row == lane^8) = 0x128
__device__ __forceinline__ float dpp_xor8_add(float v) {
  int sw = __builtin_amdgcn_update_dpp(0, __builtin_bit_cast(int, v),
                                       0x128, 0xF, 0xF, true);
  return v + __builtin_bit_cast(float, sw);
}

// reduce across lanes of the SAME parity (32 lanes): masks 2,4,8,16,32.
// 2 and 8 are DPP (VALU); 4,16,32 stay shfl (no exact xor-DPP for them).
__device__ __forceinline__ float pair_lane_reduce(float v) {
  v = dpp_xor2_add(v);
  v += __shfl_xor(v, 4, 64);
  v = dpp_xor8_add(v);
  v += __shfl_xor(v, 16, 64);
  v += __shfl_xor(v, 32, 64);
  return v;
}

// Round-6: REVERT to the session-best configuration (R1, 82.16us).
// Evidence: six structurally different kernels split into exactly two
// levels -- brute-force family 82.2-84.0us (pair/quad split, 4 vs 8
// waves/SIMD, DPP vs shfl, fused vs split tail) and factorized 3-dispatch
// family 97.5us (op count 5x lower, yet +14us; LDS-gather packing D=0.03us).
// Kernel-side op count, occupancy, LDS width all D~=0 within a family;
// totals track the ~41-43us poison fills 1:1; issue-floor arithmetic for
// the brute-force main is ~8-10us. Conclusion: timed window is dominated
// by harness-side poisoning; plateau = harness floor. If this reproduces
// ~82 +- 1, declare ROOFLINE.
__global__ __launch_bounds__(TPB)
void ssq_main(const float* __restrict__ x, const float* __restrict__ bins,
              float* __restrict__ out, float* __restrict__ partials) {
  const int tid  = threadIdx.x;
  const int half = tid & 1;                       // which 16-bin half
  const int pslot = blockIdx.x * (TPB / 2) + (tid >> 1);

  // this lane's 16 bins (VGPRs -- parity-dependent, can't be SGPR)
  float binv[KH];
#pragma unroll
  for (int j = 0; j < KH; ++j) binv[j] = bins[KH * half + j];
  float bs_local = 0.f;
#pragma unroll
  for (int j = 0; j < KH; ++j) bs_local += binv[j];
  const float binsum = dpp_xor1_add(bs_local);
  const float epsb = 1e-10f * binsum;             // eps * sum(bins) term

  float sAcc[KH];
#pragma unroll
  for (int j = 0; j < KH; ++j) sAcc[j] = 0.f;
  float q = 0.f;

  const float Ch = -7.213475204444817f;           // 0.5 * ALPHA * log2(e)

  float xv_cur = x[pslot];                        // 1-deep prefetch scalar

#pragma unroll 1
  for (int e = 0; e < EPT; ++e) {
    const float xv = xv_cur;
    if (e + 1 < EPT) xv_cur = x[pslot + (e + 1) * PSTRIDE];  // uniform branch
    float t[KH];                                  // static indices only
    float s0 = 0.f, s1 = 0.f, s2 = 0.f, s3 = 0.f;
    float h0 = 0.f, h1 = 0.f, h2 = 0.f, h3 = 0.f;
    float b0 = 0.f, b1 = 0.f, b2 = 0.f, b3 = 0.f;
#pragma unroll
    for (int j = 0; j < KH; j += 4) {
      float ha = __builtin_amdgcn_exp2f(Ch * fabsf(xv - binv[j + 0]));
      float hb = __builtin_amdgcn_exp2f(Ch * fabsf(xv - binv[j + 1]));
      float hc = __builtin_amdgcn_exp2f(Ch * fabsf(xv - binv[j + 2]));
      float hd = __builtin_amdgcn_exp2f(Ch * fabsf(xv - binv[j + 3]));
      float ta = ha * ha, tb = hb * hb, tc = hc * hc, td = hd * hd;
      t[j + 0] = ta; t[j + 1] = tb; t[j + 2] = tc; t[j + 3] = td;
      s0 += ta; s1 += tb; s2 += tc; s3 += td;
      h0 += ha; h1 += hb; h2 += hc; h3 += hd;
      b0 = fmaf(ta, binv[j + 0], b0);
      b1 = fmaf(tb, binv[j + 1], b1);
      b2 = fmaf(tc, binv[j + 2], b2);
      b3 = fmaf(td, binv[j + 3], b3);
    }
    const float s_loc = (s0 + s1) + (s2 + s3);
    const float b_loc = (b0 + b1) + (b2 + b3);
    const float s_full = dpp_xor1_add(s_loc);     // both halves, VALU-only
    const float b_full = dpp_xor1_add(b_loc);
    const float inv = __builtin_amdgcn_rcpf(s_full);
    // local hsum * rsqrt(s): summing q over ALL lanes later gives sum_k sqrt(a_k)
    q = fmaf((h0 + h1) + (h2 + h3), __builtin_amdgcn_rsqf(s_full), q);
    if (half == 0) out[pslot + e * PSTRIDE] = fmaf(b_full, inv, epsb);
#pragma unroll
    for (int j = 0; j < KH; ++j) sAcc[j] = fmaf(t[j], inv, sAcc[j]);
  }

  // block reduction. Same-parity butterfly: after it, lane0 holds bin j sum,
  // lane1 holds bin j+16 sum (for each of the 16 j's). q: full-wave reduce.
  __shared__ float red[4][K + 1];
  const int lane = tid & 63, wv = tid >> 6;
#pragma unroll
  for (int j = 0; j < KH; ++j) {
    float v = pair_lane_reduce(sAcc[j]);
    if (lane < 2) red[wv][KH * lane + j] = v;     // lane==half here
  }
  {
    float v = wave_reduce_sum(q);
    if (lane == 0) red[wv][K] = v;
  }
  __syncthreads();
  if (tid < K + 1) {
    float v = red[0][tid] + red[1][tid] + red[2][tid] + red[3][tid];
    partials[tid * NB + blockIdx.x] = v;          // written exactly once
  }
}

// 33 blocks: block c reduces partials[c*NB .. c*NB+NB) -> sums[c]
__global__ __launch_bounds__(TPB)
void ssq_reduce(const float* __restrict__ partials, float* __restrict__ sums) {
  const float* p = partials + blockIdx.x * NB;
  const int tid  = threadIdx.x;
  float s = 0.f;
#pragma unroll
  for (int j = 0; j < NB / TPB; ++j) s += p[tid + j * TPB];
  s = wave_reduce_sum(s);
  __shared__ float red[4];
  if ((tid & 63) == 0) red[tid >> 6] = s;
  __syncthreads();
  if (tid == 0) sums[blockIdx.x] = red[0] + red[1] + red[2] + red[3];
}

// one wave: entropy over 32 p_k + quant mean + tails
__global__ void ssq_final(const float* __restrict__ sums, float* __restrict__ out) {
  const int lane = threadIdx.x;
  float e = 0.f;
  if (lane < K) {
    float p = sums[lane] * (1.0f / (float)NTOT) + 1e-10f;  // eps folded in here
    e = -p * __logf(p);
  }
  e = wave_reduce_sum(e);
  if (lane == 0) {
    out[NTOT + 0] = e;                              // code entropy
    out[NTOT + 1] = 0.f;                            // TAU
    out[NTOT + 2] = sums[K] * (1.0f / (float)NTOT); // quant loss
    out[NTOT + 3] = 0.f;                            // TAU2
  }
}

extern "C" void kernel_launch(void* const* d_in, const int* in_sizes, int n_in,
                              void* d_out, int out_size, void* d_ws, size_t ws_size,
                              hipStream_t stream) {
  const float* x    = (const float*)d_in[0];
  const float* bins = (const float*)d_in[1];
  float* out        = (float*)d_out;
  float* partials   = (float*)d_ws;                 // (K+1)*NB floats = 264 KB
  float* sums       = partials + (K + 1) * NB;      // 33 floats

  ssq_main  <<<NB,    TPB, 0, stream>>>(x, bins, out, partials);
  ssq_reduce<<<K + 1, TPB, 0, stream>>>(partials, sums);
  ssq_final <<<1,     64,  0, stream>>>(sums, out);
}